// Round 21
// baseline (196.659 us; speedup 1.0000x reference)
//
#include <hip/hip_runtime.h>
#include <hip/hip_bf16.h>
#include <math.h>

// Problem constants
#define BS   8
#define NSEQ 1025
#define DIM  768
#define C3   2304      // 3*DIM
#define HEADS 12
#define DH   64
#define MROWS (BS*NSEQ) // 8200
#define MPAD  8448      // 66*128, padded M for GEMM tiles
#define NKPAD 1088      // 17*64, padded key length for MFMA tiles
#define QPAD  1152      // 9*128, padded query length for attn blocks
#define NBH   (BS*HEADS)

// log2(e) folded into Q during LN so softmax uses exp2
#define QSCALE (0.125f * 1.44269504088896340736f)
#define SBOUND 10.0f    // fixed softmax offset (log2 domain); ratios unchanged

typedef __attribute__((ext_vector_type(8))) short bf16x8;
typedef __attribute__((ext_vector_type(4))) float f32x4;

static __device__ __forceinline__ unsigned short f2bf(float f) {
  unsigned int u = __float_as_uint(f);
  unsigned int r = (u + 0x7fffu + ((u >> 16) & 1u)) >> 16;
  return (unsigned short)r;
}

static __device__ __forceinline__ float bf2f(short u) {
  return __uint_as_float(((unsigned int)(unsigned short)u) << 16);
}

// packed f32x2 -> bf16x2 (RNE) in one instruction; low half = a, high = b
static __device__ __forceinline__ unsigned int cvtpk_bf16(float a, float b) {
  unsigned int r;
  asm("v_cvt_pk_bf16_f32 %0, %1, %2" : "=v"(r) : "v"(a), "v"(b));
  return r;
}

static __device__ __forceinline__ void gload16(const short* g, short* l) {
  __builtin_amdgcn_global_load_lds(
      (const __attribute__((address_space(1))) unsigned int*)g,
      (__attribute__((address_space(3))) unsigned int*)l, 16, 0, 0);
}

// ---------------------------------------------------------------------------
// x fp32 [MROWS][DIM] -> xb bf16 [MPAD][DIM], pad rows zeroed.
// ---------------------------------------------------------------------------
__global__ __launch_bounds__(256) void convert_x_kernel(
    const float* __restrict__ x, short* __restrict__ xb) {
  const size_t i = ((size_t)blockIdx.x * 256 + threadIdx.x) * 8;
  const size_t row = i / DIM;
  bf16x8 w;
  if (row < MROWS) {
    float4 v0 = *(const float4*)&x[i];
    float4 v1 = *(const float4*)&x[i + 4];
    w[0] = (short)f2bf(v0.x); w[1] = (short)f2bf(v0.y);
    w[2] = (short)f2bf(v0.z); w[3] = (short)f2bf(v0.w);
    w[4] = (short)f2bf(v1.x); w[5] = (short)f2bf(v1.y);
    w[6] = (short)f2bf(v1.z); w[7] = (short)f2bf(v1.w);
  } else {
    #pragma unroll
    for (int j = 0; j < 8; ++j) w[j] = 0;
  }
  *(bf16x8*)&xb[i] = w;
}

// ---------------------------------------------------------------------------
// W fp32 [K][N] -> Wt bf16 [N][K] (transpose + convert). Grid (N/64, K/64).
// ---------------------------------------------------------------------------
__global__ __launch_bounds__(256) void wtrans_kernel(
    const float* __restrict__ W, short* __restrict__ Wt, int K, int N) {
  const int n0 = blockIdx.x * 64, k0 = blockIdx.y * 64;
  __shared__ float tile[64][65];
  const int r = threadIdx.x >> 2;        // 0..63
  const int c0 = (threadIdx.x & 3) * 16; // 0,16,32,48
  const float* src = W + (size_t)(k0 + r) * N + n0 + c0;
  #pragma unroll
  for (int j = 0; j < 16; j += 4) {
    float4 v = *(const float4*)(src + j);
    tile[r][c0 + j]     = v.x;
    tile[r][c0 + j + 1] = v.y;
    tile[r][c0 + j + 2] = v.z;
    tile[r][c0 + j + 3] = v.w;
  }
  __syncthreads();
  bf16x8 w0, w1;
  #pragma unroll
  for (int j = 0; j < 8; ++j) {
    w0[j] = (short)f2bf(tile[c0 + j][r]);
    w1[j] = (short)f2bf(tile[c0 + 8 + j][r]);
  }
  short* dst = Wt + (size_t)(n0 + r) * K + k0 + c0;
  *(bf16x8*)dst = w0;
  *(bf16x8*)(dst + 8) = w1;
}

// ---------------------------------------------------------------------------
// Fused QKV GEMM + LayerNorm. 128x128 tile, BK=64, 4 waves.
// R17-proven: counted s_waitcnt vmcnt(8) + raw s_barrier pipelined staging,
// XOR-swizzled LDS. R21: v-heads write DIRECTLY into the transposed vt
// layout (vt[bh][d][key]) -- same values as before, different addresses --
// eliminating the vt_convert kernel. vt pad-key columns stay uninitialized:
// provably harmless (attn masks P=0 for keys>=1025; 0 x finite = 0).
// ---------------------------------------------------------------------------
__global__ __launch_bounds__(256) void gemm_qkv_kernel(
    const short* __restrict__ A, const short* __restrict__ Bt,
    const float* __restrict__ bias,
    const float* __restrict__ gq, const float* __restrict__ bq,
    const float* __restrict__ gk, const float* __restrict__ bk,
    short* __restrict__ qb, short* __restrict__ kb, short* __restrict__ vt) {
  __shared__ short As[2][128 * 64];
  __shared__ short Bs[2][128 * 64];
  const int tid = threadIdx.x;
  const int wid = tid >> 6, lane = tid & 63;
  const int lo = lane & 15, hi = lane >> 4;
  const int wr = wid >> 1, wc = wid & 1;
  const int xsw = (lo & 7) << 3;                      // read-side XOR (shorts)

  const int nwg = gridDim.x * gridDim.y;
  int bid = blockIdx.y * gridDim.x + blockIdx.x;
  {
    const int q = nwg >> 3, rr = nwg & 7;
    const int xcd = bid & 7, idx = bid >> 3;
    bid = (xcd < rr ? xcd * (q + 1) : rr * (q + 1) + (xcd - rr) * q) + idx;
  }
  const int m0 = (bid / gridDim.x) * 128, n0 = (bid % gridDim.x) * 128;

  const int rl = lane >> 3;
  const int sw = ((lane & 7) ^ (lane >> 3)) << 3;     // pre-swizzled src col

  f32x4 acc[4][4];
  #pragma unroll
  for (int m = 0; m < 4; ++m)
    #pragma unroll
    for (int n = 0; n < 4; ++n)
      acc[m][n][0] = acc[m][n][1] = acc[m][n][2] = acc[m][n][3] = 0.f;

  const short* Abase = A + (size_t)(m0 + wid * 32 + rl) * DIM + sw;
  const short* Bbase = Bt + (size_t)(n0 + wid * 32 + rl) * DIM + sw;

  auto stage = [&](int bf, int k0) {   // 8 global_load_lds per wave
    #pragma unroll
    for (int i = 0; i < 4; ++i) {
      gload16(Abase + (size_t)(i * 8) * DIM + k0, &As[bf][(wid * 32 + i * 8) * 64]);
      gload16(Bbase + (size_t)(i * 8) * DIM + k0, &Bs[bf][(wid * 32 + i * 8) * 64]);
    }
  };

  const int NT = DIM / 64;   // 12
  stage(0, 0);
  stage(1, 64);
  asm volatile("s_waitcnt vmcnt(8)\n\ts_barrier" ::: "memory");  // tile0 ready
  int bf = 0;
  for (int t = 0; t < NT; ++t) {
    #pragma unroll
    for (int kk = 0; kk < 2; ++kk) {
      bf16x8 a[4], bfr[4];
      #pragma unroll
      for (int m = 0; m < 4; ++m)
        a[m] = *(const bf16x8*)&As[bf][(wr * 64 + m * 16 + lo) * 64
                                       + ((kk * 32 + hi * 8) ^ xsw)];
      #pragma unroll
      for (int n = 0; n < 4; ++n)
        bfr[n] = *(const bf16x8*)&Bs[bf][(wc * 64 + n * 16 + lo) * 64
                                         + ((kk * 32 + hi * 8) ^ xsw)];
      #pragma unroll
      for (int m = 0; m < 4; ++m)
        #pragma unroll
        for (int n = 0; n < 4; ++n)
          acc[m][n] = __builtin_amdgcn_mfma_f32_16x16x32_bf16(a[m], bfr[n], acc[m][n], 0, 0, 0);
    }
    if (t < NT - 1) {
      asm volatile("s_barrier" ::: "memory");          // all done reading bf
      if (t + 2 < NT) {
        stage(bf, (t + 2) * 64);                       // into bf; in flight
        asm volatile("s_waitcnt vmcnt(8)\n\ts_barrier" ::: "memory"); // t+1 ready
      } else {
        asm volatile("s_waitcnt vmcnt(0)\n\ts_barrier" ::: "memory"); // last tile
      }
    }
    bf ^= 1;
  }

  // ---- fused epilogue (bitwise-identical LN butterfly) ----
  const int col0 = n0 + wc * 64;           // 64-aligned => one head per wave
  const int hglob = col0 >> 6;             // 0..35
  const int htype = hglob / HEADS;         // 0=q 1=k 2=v
  const int hidx  = hglob - htype * HEADS;
  const float* bp = bias + col0 + lo;

  float gl[4], bl[4];
  if (htype == 0) {
    #pragma unroll
    for (int nt = 0; nt < 4; ++nt) { gl[nt] = gq[nt * 16 + lo]; bl[nt] = bq[nt * 16 + lo]; }
  } else if (htype == 1) {
    #pragma unroll
    for (int nt = 0; nt < 4; ++nt) { gl[nt] = gk[nt * 16 + lo]; bl[nt] = bk[nt * 16 + lo]; }
  }

  #pragma unroll
  for (int m = 0; m < 4; ++m) {
    #pragma unroll
    for (int r = 0; r < 4; ++r) {
      const int grow = m0 + wr * 64 + m * 16 + hi * 4 + r;
      if (grow < MROWS) {          // uniform across each 16-lane lo-group
        const int brow = grow / NSEQ;
        const int n1 = grow - brow * NSEQ;
        const int bh = brow * HEADS + hidx;
        float v[4];
        #pragma unroll
        for (int nt = 0; nt < 4; ++nt) v[nt] = acc[m][nt][r] + bp[nt * 16];
        if (htype == 2) {
          // transposed store: vt[bh][d = nt*16+lo][key = n1]
          short* dstv = vt + (size_t)bh * DH * NKPAD + n1;
          #pragma unroll
          for (int nt = 0; nt < 4; ++nt)
            dstv[(size_t)(nt * 16 + lo) * NKPAD] = (short)f2bf(v[nt]);
        } else {
          // exact butterfly emulation (same operand pairing as ln_qk):
          float s2v[4];
          #pragma unroll
          for (int nt = 0; nt < 4; ++nt) s2v[nt] = v[nt] * v[nt];
          float t[4], t2[4];
          #pragma unroll
          for (int nt = 0; nt < 4; ++nt) {    // off = 32  (d^32 <=> nt^2)
            t[nt]  = v[nt]   + v[nt ^ 2];
            t2[nt] = s2v[nt] + s2v[nt ^ 2];
          }
          float u  = t[0]  + t[1];            // off = 16  (nt^1; all nt equal)
          float u2 = t2[0] + t2[1];
          u  += __shfl_xor(u,  8);  u2 += __shfl_xor(u2, 8);   // off = 8
          u  += __shfl_xor(u,  4);  u2 += __shfl_xor(u2, 4);   // off = 4
          u  += __shfl_xor(u,  2);  u2 += __shfl_xor(u2, 2);   // off = 2
          u  += __shfl_xor(u,  1);  u2 += __shfl_xor(u2, 1);   // off = 1
          const float inv64 = 1.f / 64.f;
          const float mean = u * inv64;
          const float var  = u2 * inv64 - mean * mean;
          const float rr = rsqrtf(var + 1e-5f);
          if (htype == 0) {
            short* dst = qb + ((size_t)bh * QPAD + n1) * DH + lo;
            #pragma unroll
            for (int nt = 0; nt < 4; ++nt)
              dst[nt * 16] = (short)f2bf(((v[nt] - mean) * rr * gl[nt] + bl[nt]) * QSCALE);
          } else {
            short* dst = kb + ((size_t)bh * NKPAD + n1) * DH + lo;
            #pragma unroll
            for (int nt = 0; nt < 4; ++nt)
              dst[nt * 16] = (short)f2bf((v[nt] - mean) * rr * gl[nt] + bl[nt]);
          }
        }
      }
    }
  }
}

// ---------------------------------------------------------------------------
// Generic bf16 MFMA GEMM (proj): C[M,N]f32 = A . Bt^T + bias. 128x128 tile,
// R17-proven counted-vmcnt pipelined staging + swizzled LDS.
// ---------------------------------------------------------------------------
__global__ __launch_bounds__(256) void gemm_bf16_kernel(
    const short* __restrict__ A, const short* __restrict__ Bt,
    const float* __restrict__ bias, float* __restrict__ C,
    int M, int N, int K) {
  __shared__ short As[2][128 * 64];
  __shared__ short Bs[2][128 * 64];
  const int tid = threadIdx.x;
  const int wid = tid >> 6, lane = tid & 63;
  const int lo = lane & 15, hi = lane >> 4;
  const int wr = wid >> 1, wc = wid & 1;
  const int xsw = (lo & 7) << 3;

  const int nwg = gridDim.x * gridDim.y;
  int bid = blockIdx.y * gridDim.x + blockIdx.x;
  {
    const int q = nwg >> 3, rr = nwg & 7;
    const int xcd = bid & 7, idx = bid >> 3;
    bid = (xcd < rr ? xcd * (q + 1) : rr * (q + 1) + (xcd - rr) * q) + idx;
  }
  const int m0 = (bid / gridDim.x) * 128, n0 = (bid % gridDim.x) * 128;

  const int rl = lane >> 3;
  const int sw = ((lane & 7) ^ (lane >> 3)) << 3;

  f32x4 acc[4][4];
  #pragma unroll
  for (int m = 0; m < 4; ++m)
    #pragma unroll
    for (int n = 0; n < 4; ++n)
      acc[m][n][0] = acc[m][n][1] = acc[m][n][2] = acc[m][n][3] = 0.f;

  const short* Abase = A + (size_t)(m0 + wid * 32 + rl) * K + sw;
  const short* Bbase = Bt + (size_t)(n0 + wid * 32 + rl) * K + sw;

  auto stage = [&](int bf, int k0) {   // 8 global_load_lds per wave
    #pragma unroll
    for (int i = 0; i < 4; ++i) {
      gload16(Abase + (size_t)(i * 8) * K + k0, &As[bf][(wid * 32 + i * 8) * 64]);
      gload16(Bbase + (size_t)(i * 8) * K + k0, &Bs[bf][(wid * 32 + i * 8) * 64]);
    }
  };

  const int NT = K / 64;
  stage(0, 0);
  if (NT > 1) stage(1, 64);
  asm volatile("s_waitcnt vmcnt(8)\n\ts_barrier" ::: "memory");
  int bf = 0;
  for (int t = 0; t < NT; ++t) {
    #pragma unroll
    for (int kk = 0; kk < 2; ++kk) {
      bf16x8 a[4], bfr[4];
      #pragma unroll
      for (int m = 0; m < 4; ++m)
        a[m] = *(const bf16x8*)&As[bf][(wr * 64 + m * 16 + lo) * 64
                                       + ((kk * 32 + hi * 8) ^ xsw)];
      #pragma unroll
      for (int n = 0; n < 4; ++n)
        bfr[n] = *(const bf16x8*)&Bs[bf][(wc * 64 + n * 16 + lo) * 64
                                         + ((kk * 32 + hi * 8) ^ xsw)];
      #pragma unroll
      for (int m = 0; m < 4; ++m)
        #pragma unroll
        for (int n = 0; n < 4; ++n)
          acc[m][n] = __builtin_amdgcn_mfma_f32_16x16x32_bf16(a[m], bfr[n], acc[m][n], 0, 0, 0);
    }
    if (t < NT - 1) {
      asm volatile("s_barrier" ::: "memory");
      if (t + 2 < NT) {
        stage(bf, (t + 2) * 64);
        asm volatile("s_waitcnt vmcnt(8)\n\ts_barrier" ::: "memory");
      } else {
        asm volatile("s_waitcnt vmcnt(0)\n\ts_barrier" ::: "memory");
      }
    }
    bf ^= 1;
  }

  #pragma unroll
  for (int m = 0; m < 4; ++m) {
    #pragma unroll
    for (int r = 0; r < 4; ++r) {
      const int grow = m0 + wr * 64 + m * 16 + hi * 4 + r;
      if (grow < M) {
        float* cp = C + (size_t)grow * N + n0 + wc * 64 + lo;
        const float* bp = bias + n0 + wc * 64 + lo;
        #pragma unroll
        for (int n = 0; n < 4; ++n) cp[n * 16] = acc[m][n][r] + bp[n * 16];
      }
    }
  }
}

// ---------------------------------------------------------------------------
// MFMA bf16 flash attention v7 (R20): split-stage single-buffered K/V +
// ones-MFMA denominator. Grid: (96, QPAD/128 = 9) -- XCD-local.
// ---------------------------------------------------------------------------
__global__ __launch_bounds__(256) void attn_mfma_kernel(
    const short* __restrict__ qb, const short* __restrict__ kb,
    const short* __restrict__ vt, short* __restrict__ ab) {
  const int bh = blockIdx.x;
  const int b = bh / HEADS, h = bh - (bh / HEADS) * HEADS;
  const int wid = threadIdx.x >> 6;
  const int lane = threadIdx.x & 63;
  const int lo = lane & 15, hi = lane >> 4;
  const int q0 = blockIdx.y * 128;
  const int xsw = (lo & 7) << 3;          // read-side XOR swizzle (shorts)

  __shared__ short Ks[64 * 64];           // swizzled K tile  [key][d]
  __shared__ short Vs[64 * 64];           // swizzled V^T tile [d][key]
  __shared__ short Pb[4][32][72];         // per-wave P buffer

  const short* kg = kb + (size_t)bh * NKPAD * DH;
  const short* vg = vt + (size_t)bh * DH * NKPAD;

  const int sr = wid * 16 + (lane >> 3);               // staging row 0..63
  const int sw = ((lane & 7) ^ (lane >> 3)) << 3;      // pre-swizzled col
  auto stageK = [&](int kt) {
    #pragma unroll
    for (int i = 0; i < 2; ++i)
      gload16(kg + (size_t)(kt * 64 + sr + i * 8) * DH + sw,
              &Ks[wid * 1024 + i * 512]);
  };
  auto stageV = [&](int kt) {
    #pragma unroll
    for (int i = 0; i < 2; ++i)
      gload16(vg + (size_t)(sr + i * 8) * NKPAD + kt * 64 + sw,
              &Vs[wid * 1024 + i * 512]);
  };

  bf16x8 aq[2][2];
  #pragma unroll
  for (int m = 0; m < 2; ++m) {
    const short* qp = qb + (size_t)bh * QPAD * DH
                    + (size_t)(q0 + wid * 32 + m * 16 + lo) * DH + hi * 8;
    aq[m][0] = *(const bf16x8*)qp;
    aq[m][1] = *(const bf16x8*)(qp + 32);
  }

  // ones B-fragment for the denominator MFMA (bf16 1.0 = 0x3F80)
  bf16x8 ones;
  #pragma unroll
  for (int j = 0; j < 8; ++j) ones[j] = (short)0x3F80;

  f32x4 o[2][4];
  f32x4 ol[2];                            // row-sum accumulator (denominator)
  #pragma unroll
  for (int m = 0; m < 2; ++m) {
    #pragma unroll
    for (int nt = 0; nt < 4; ++nt)
      o[m][nt][0] = o[m][nt][1] = o[m][nt][2] = o[m][nt][3] = 0.f;
    ol[m][0] = ol[m][1] = ol[m][2] = ol[m][3] = 0.f;
  }

  stageK(0);
  stageV(0);
  __syncthreads();   // drains vmcnt(0): tile 0 staged & visible

  for (int kt = 0; kt < 17; ++kt) {
    // ---- QK^T (reads Ks) ----
    f32x4 s[2][4];
    #pragma unroll
    for (int m = 0; m < 2; ++m)
      #pragma unroll
      for (int nt = 0; nt < 4; ++nt)
        s[m][nt][0] = s[m][nt][1] = s[m][nt][2] = s[m][nt][3] = 0.f;
    __builtin_amdgcn_s_setprio(1);
    #pragma unroll
    for (int kk = 0; kk < 2; ++kk) {
      bf16x8 kf[4];
      #pragma unroll
      for (int nt = 0; nt < 4; ++nt)
        kf[nt] = *(const bf16x8*)&Ks[(nt * 16 + lo) * 64
                                     + ((kk * 32 + hi * 8) ^ xsw)];
      #pragma unroll
      for (int m = 0; m < 2; ++m)
        #pragma unroll
        for (int nt = 0; nt < 4; ++nt)
          s[m][nt] = __builtin_amdgcn_mfma_f32_16x16x32_bf16(
              aq[m][kk], kf[nt], s[m][nt], 0, 0, 0);
    }
    __builtin_amdgcn_s_setprio(0);

    __syncthreads();                  // all waves done reading Ks
    if (kt < 16) stageK(kt + 1);      // overlaps softmax + PV below

    if (kt == 16) {
      #pragma unroll
      for (int m = 0; m < 2; ++m)
        #pragma unroll
        for (int nt = 0; nt < 4; ++nt)
          if (nt * 16 + lo >= 1)
            s[m][nt][0] = s[m][nt][1] = s[m][nt][2] = s[m][nt][3] = -1e30f;
    }
    // ---- softmax (fixed offset) + P staging (packed bf16 convert) ----
    #pragma unroll
    for (int m = 0; m < 2; ++m)
      #pragma unroll
      for (int nt = 0; nt < 4; ++nt) {
        float p0 = exp2f(s[m][nt][0] - SBOUND);
        float p1 = exp2f(s[m][nt][1] - SBOUND);
        float p2 = exp2f(s[m][nt][2] - SBOUND);
        float p3 = exp2f(s[m][nt][3] - SBOUND);
        unsigned int c01 = cvtpk_bf16(p0, p1);
        unsigned int c23 = cvtpk_bf16(p2, p3);
        unsigned short* pb = (unsigned short*)&Pb[wid][m * 16 + 4 * hi][nt * 16 + lo];
        pb[0]       = (unsigned short)c01;
        pb[72]      = (unsigned short)(c01 >> 16);
        pb[144]     = (unsigned short)c23;
        pb[216]     = (unsigned short)(c23 >> 16);
      }
    // ---- PV (reads Vs) + denominator via ones-MFMA ----
    __builtin_amdgcn_s_setprio(1);
    #pragma unroll
    for (int ks = 0; ks < 2; ++ks) {
      bf16x8 pa0 = *(const bf16x8*)&Pb[wid][lo][ks * 32 + hi * 8];
      bf16x8 pa1 = *(const bf16x8*)&Pb[wid][16 + lo][ks * 32 + hi * 8];
      #pragma unroll
      for (int nt = 0; nt < 4; ++nt) {
        bf16x8 vf = *(const bf16x8*)&Vs[(nt * 16 + lo) * 64
                                        + ((ks * 32 + hi * 8) ^ xsw)];
        o[0][nt] = __builtin_amdgcn_mfma_f32_16x16x32_bf16(pa0, vf, o[0][nt], 0, 0, 0);
        o[1][nt] = __builtin_amdgcn_mfma_f32_16x16x32_bf16(pa1, vf, o[1][nt], 0, 0, 0);
      }
      ol[0] = __builtin_amdgcn_mfma_f32_16x16x32_bf16(pa0, ones, ol[0], 0, 0, 0);
      ol[1] = __builtin_amdgcn_mfma_f32_16x16x32_bf16(pa1, ones, ol[1], 0, 0, 0);
    }
    __builtin_amdgcn_s_setprio(0);

    __syncthreads();                  // all waves done reading Vs; drains
    if (kt < 16) stageV(kt + 1);      //   stageK's vmcnt. V overlaps next QK^T
  }

  // ol[m][r] = row sum (denominator) for row m*16 + 4*hi + r -- no reduce.
  #pragma unroll
  for (int m = 0; m < 2; ++m)
    #pragma unroll
    for (int r = 0; r < 4; ++r) {
      const int qrow = q0 + wid * 32 + m * 16 + 4 * hi + r;
      if (qrow < NSEQ) {
        const float inv = 1.f / ol[m][r];
        short* op = ab + (size_t)(b * NSEQ + qrow) * DIM + h * DH + lo;
        #pragma unroll
        for (int nt = 0; nt < 4; ++nt)
          op[nt * 16] = (short)f2bf(o[m][nt][r] * inv);
      }
    }
}

// ---------------------------------------------------------------------------
// attn_map pass A: per-(b,h) row-0 softmax max & inv-denominator (bf16 in).
// Grid 96, 256 threads. ms[bh] = {max, 1/(sum*HEADS)}.
// ---------------------------------------------------------------------------
__global__ __launch_bounds__(256) void map_ms_kernel(
    const short* __restrict__ qb, const short* __restrict__ kb,
    float* __restrict__ ms) {
  const int bh = blockIdx.x;
  const int tid = threadIdx.x;
  __shared__ float q0s[64];
  __shared__ float red[256];
  if (tid < 64) q0s[tid] = bf2f(qb[(size_t)bh * QPAD * DH + tid]);
  __syncthreads();
  float s[5];
  float lm = -INFINITY;
  #pragma unroll
  for (int sl = 0; sl < 5; ++sl) {
    int j = tid + sl * 256;
    s[sl] = -INFINITY;
    if (j < NSEQ) {
      const short* kp = kb + ((size_t)bh * NKPAD + j) * DH;
      float d0 = 0.f;
      #pragma unroll
      for (int c = 0; c < 8; ++c) {
        bf16x8 kv = *(const bf16x8*)(kp + c * 8);
        #pragma unroll
        for (int e = 0; e < 8; ++e) d0 += q0s[c * 8 + e] * bf2f(kv[e]);
      }
      s[sl] = d0;
      lm = fmaxf(lm, d0);
    }
  }
  red[tid] = lm; __syncthreads();
  for (int off = 128; off > 0; off >>= 1) {
    if (tid < off) red[tid] = fmaxf(red[tid], red[tid + off]);
    __syncthreads();
  }
  const float Mx = red[0]; __syncthreads();
  float ls = 0.f;
  #pragma unroll
  for (int sl = 0; sl < 5; ++sl) {
    int j = tid + sl * 256;
    if (j < NSEQ) ls += exp2f(s[sl] - Mx);
  }
  red[tid] = ls; __syncthreads();
  for (int off = 128; off > 0; off >>= 1) {
    if (tid < off) red[tid] += red[tid + off];
    __syncthreads();
  }
  if (tid == 0) {
    ms[bh * 2]     = Mx;
    ms[bh * 2 + 1] = 1.f / (red[0] * (float)HEADS);
  }
}

// ---------------------------------------------------------------------------
// attn_map pass B: map[b][j-1] = sum_h exp2(q0_h . k_jh - M_h) * inv_h.
// Grid (4, 8), 256 threads; thread handles one (b, j). bf16 inputs.
// ---------------------------------------------------------------------------
__global__ __launch_bounds__(256) void map_p_kernel(
    const short* __restrict__ qb, const short* __restrict__ kb,
    const float* __restrict__ ms, float* __restrict__ map) {
  const int b = blockIdx.y;
  const int j = blockIdx.x * 256 + threadIdx.x + 1;   // 1..1024
  const int tid = threadIdx.x;
  __shared__ float q0s[768];
  __shared__ float msb[24];
  for (int idx = tid; idx < 768; idx += 256) {
    const int h = idx >> 6, d = idx & 63;
    q0s[idx] = bf2f(qb[(size_t)(b * HEADS + h) * QPAD * DH + d]);
  }
  if (tid < 24) msb[tid] = ms[b * HEADS * 2 + tid];
  __syncthreads();
  float acc = 0.f;
  #pragma unroll
  for (int h = 0; h < HEADS; ++h) {
    const short* kp = kb + ((size_t)(b * HEADS + h) * NKPAD + j) * DH;
    float d0 = 0.f;
    #pragma unroll
    for (int c = 0; c < 8; ++c) {
      bf16x8 kv = *(const bf16x8*)(kp + c * 8);
      const float* qp = &q0s[h * DH + c * 8];
      #pragma unroll
      for (int e = 0; e < 8; ++e) d0 += qp[e] * bf2f(kv[e]);
    }
    acc += exp2f(d0 - msb[h * 2]) * msb[h * 2 + 1];
  }
  map[(size_t)b * (NSEQ - 1) + j - 1] = acc;
}

// ---------------------------------------------------------------------------
extern "C" void kernel_launch(void* const* d_in, const int* in_sizes, int n_in,
                              void* d_out, int out_size, void* d_ws, size_t ws_size,
                              hipStream_t stream) {
  const float* x     = (const float*)d_in[0];
  const float* Wqkv  = (const float*)d_in[1];
  const float* bqkv  = (const float*)d_in[2];
  const float* Wproj = (const float*)d_in[3];
  const float* bproj = (const float*)d_in[4];
  const float* gq    = (const float*)d_in[5];
  const float* betaq = (const float*)d_in[6];
  const float* gk    = (const float*)d_in[7];
  const float* betak = (const float*)d_in[8];

  short* xb  = (short*)d_ws;                              // [8448,768] bf16 (also attn out)
  short* qb  = xb + (size_t)MPAD * DIM;                   // [96,1152,64] bf16
  short* kb  = qb + (size_t)NBH * QPAD * DH;              // [96,1088,64] bf16
  short* vt  = kb + (size_t)NBH * NKPAD * DH;             // [96,64,1088] bf16
  short* wqt = vt + (size_t)NBH * DH * NKPAD;             // [2304,768] bf16
  short* wpt = wqt + (size_t)C3 * DIM;                    // [768,768] bf16
  float* ms  = (float*)(wpt + (size_t)DIM * DIM);         // [96,2] f32
  float* out = (float*)d_out;                             // [8200,768]
  float* map = out + (size_t)MROWS * DIM;                 // [8,1024]

  // 0) conversions
  convert_x_kernel<<<MPAD * DIM / 2048, 256, 0, stream>>>(x, xb);
  {
    dim3 grid(C3 / 64, DIM / 64);
    wtrans_kernel<<<grid, 256, 0, stream>>>(Wqkv, wqt, DIM, C3);
  }
  {
    dim3 grid(DIM / 64, DIM / 64);
    wtrans_kernel<<<grid, 256, 0, stream>>>(Wproj, wpt, DIM, DIM);
  }
  // 1) Fused QKV GEMM + LN -> qb/kb bf16, v written transposed into vt
  {
    dim3 grid(C3 / 128, MPAD / 128);
    gemm_qkv_kernel<<<grid, 256, 0, stream>>>(xb, wqt, bqkv,
                                              gq, betaq, gk, betak, qb, kb, vt);
  }
  // 2) MFMA attention v7 (split-stage, ones-MFMA denominator) -> bf16 into xb
  {
    dim3 grid(NBH, QPAD / 128);
    attn_mfma_kernel<<<grid, 256, 0, stream>>>(qb, kb, vt, xb);
  }
  // 3) attn_map (bf16 path, two passes)
  map_ms_kernel<<<NBH, 256, 0, stream>>>(qb, kb, ms);
  {
    dim3 grid(4, BS);
    map_p_kernel<<<grid, 256, 0, stream>>>(qb, kb, ms, map);
  }
  // 4) out = attn_out @ Wproj + bproj (pipelined vmcnt staging)
  {
    dim3 grid(DIM / 128, MPAD / 128);
    gemm_bf16_kernel<<<grid, 256, 0, stream>>>(xb, wpt, bproj, out, MROWS, DIM, DIM);
  }
}

// Round 22
// 193.196 us; speedup vs baseline: 1.0179x; 1.0179x over previous
//
#include <hip/hip_runtime.h>
#include <hip/hip_bf16.h>
#include <math.h>

// Problem constants
#define BS   8
#define NSEQ 1025
#define DIM  768
#define C3   2304      // 3*DIM
#define HEADS 12
#define DH   64
#define MROWS (BS*NSEQ) // 8200
#define MPAD  8448      // 66*128, padded M for GEMM tiles
#define NKPAD 1088      // 17*64, padded key length for MFMA tiles
#define QPAD  1152      // 9*128, padded query length for attn blocks
#define NBH   (BS*HEADS)

// log2(e) folded into Q during LN so softmax uses exp2
#define QSCALE (0.125f * 1.44269504088896340736f)
#define SBOUND 10.0f    // fixed softmax offset (log2 domain); ratios unchanged

typedef __attribute__((ext_vector_type(8))) short bf16x8;
typedef __attribute__((ext_vector_type(4))) float f32x4;

static __device__ __forceinline__ unsigned short f2bf(float f) {
  unsigned int u = __float_as_uint(f);
  unsigned int r = (u + 0x7fffu + ((u >> 16) & 1u)) >> 16;
  return (unsigned short)r;
}

static __device__ __forceinline__ float bf2f(short u) {
  return __uint_as_float(((unsigned int)(unsigned short)u) << 16);
}

// packed f32x2 -> bf16x2 (RNE) in one instruction; low half = a, high = b
static __device__ __forceinline__ unsigned int cvtpk_bf16(float a, float b) {
  unsigned int r;
  asm("v_cvt_pk_bf16_f32 %0, %1, %2" : "=v"(r) : "v"(a), "v"(b));
  return r;
}

static __device__ __forceinline__ void gload16(const short* g, short* l) {
  __builtin_amdgcn_global_load_lds(
      (const __attribute__((address_space(1))) unsigned int*)g,
      (__attribute__((address_space(3))) unsigned int*)l, 16, 0, 0);
}

// ---------------------------------------------------------------------------
// x fp32 [MROWS][DIM] -> xb bf16 [MPAD][DIM], pad rows zeroed.
// ---------------------------------------------------------------------------
__global__ __launch_bounds__(256) void convert_x_kernel(
    const float* __restrict__ x, short* __restrict__ xb) {
  const size_t i = ((size_t)blockIdx.x * 256 + threadIdx.x) * 8;
  const size_t row = i / DIM;
  bf16x8 w;
  if (row < MROWS) {
    float4 v0 = *(const float4*)&x[i];
    float4 v1 = *(const float4*)&x[i + 4];
    w[0] = (short)f2bf(v0.x); w[1] = (short)f2bf(v0.y);
    w[2] = (short)f2bf(v0.z); w[3] = (short)f2bf(v0.w);
    w[4] = (short)f2bf(v1.x); w[5] = (short)f2bf(v1.y);
    w[6] = (short)f2bf(v1.z); w[7] = (short)f2bf(v1.w);
  } else {
    #pragma unroll
    for (int j = 0; j < 8; ++j) w[j] = 0;
  }
  *(bf16x8*)&xb[i] = w;
}

// ---------------------------------------------------------------------------
// W fp32 [K][N] -> Wt bf16 [N][K] (transpose + convert). Grid (N/64, K/64).
// ---------------------------------------------------------------------------
__global__ __launch_bounds__(256) void wtrans_kernel(
    const float* __restrict__ W, short* __restrict__ Wt, int K, int N) {
  const int n0 = blockIdx.x * 64, k0 = blockIdx.y * 64;
  __shared__ float tile[64][65];
  const int r = threadIdx.x >> 2;        // 0..63
  const int c0 = (threadIdx.x & 3) * 16; // 0,16,32,48
  const float* src = W + (size_t)(k0 + r) * N + n0 + c0;
  #pragma unroll
  for (int j = 0; j < 16; j += 4) {
    float4 v = *(const float4*)(src + j);
    tile[r][c0 + j]     = v.x;
    tile[r][c0 + j + 1] = v.y;
    tile[r][c0 + j + 2] = v.z;
    tile[r][c0 + j + 3] = v.w;
  }
  __syncthreads();
  bf16x8 w0, w1;
  #pragma unroll
  for (int j = 0; j < 8; ++j) {
    w0[j] = (short)f2bf(tile[c0 + j][r]);
    w1[j] = (short)f2bf(tile[c0 + 8 + j][r]);
  }
  short* dst = Wt + (size_t)(n0 + r) * K + k0 + c0;
  *(bf16x8*)dst = w0;
  *(bf16x8*)(dst + 8) = w1;
}

// ---------------------------------------------------------------------------
// Fused QKV GEMM + LayerNorm. 128x128 tile, BK=64, 4 waves.
// R17-proven: counted s_waitcnt vmcnt(8) + raw s_barrier pipelined staging,
// XOR-swizzled LDS. Outputs bitwise-identical to R13.
// ---------------------------------------------------------------------------
__global__ __launch_bounds__(256) void gemm_qkv_kernel(
    const short* __restrict__ A, const short* __restrict__ Bt,
    const float* __restrict__ bias,
    const float* __restrict__ gq, const float* __restrict__ bq,
    const float* __restrict__ gk, const float* __restrict__ bk,
    short* __restrict__ qb, short* __restrict__ kb, short* __restrict__ vb) {
  __shared__ short As[2][128 * 64];
  __shared__ short Bs[2][128 * 64];
  const int tid = threadIdx.x;
  const int wid = tid >> 6, lane = tid & 63;
  const int lo = lane & 15, hi = lane >> 4;
  const int wr = wid >> 1, wc = wid & 1;
  const int xsw = (lo & 7) << 3;                      // read-side XOR (shorts)

  const int nwg = gridDim.x * gridDim.y;
  int bid = blockIdx.y * gridDim.x + blockIdx.x;
  {
    const int q = nwg >> 3, rr = nwg & 7;
    const int xcd = bid & 7, idx = bid >> 3;
    bid = (xcd < rr ? xcd * (q + 1) : rr * (q + 1) + (xcd - rr) * q) + idx;
  }
  const int m0 = (bid / gridDim.x) * 128, n0 = (bid % gridDim.x) * 128;

  const int rl = lane >> 3;
  const int sw = ((lane & 7) ^ (lane >> 3)) << 3;     // pre-swizzled src col

  f32x4 acc[4][4];
  #pragma unroll
  for (int m = 0; m < 4; ++m)
    #pragma unroll
    for (int n = 0; n < 4; ++n)
      acc[m][n][0] = acc[m][n][1] = acc[m][n][2] = acc[m][n][3] = 0.f;

  const short* Abase = A + (size_t)(m0 + wid * 32 + rl) * DIM + sw;
  const short* Bbase = Bt + (size_t)(n0 + wid * 32 + rl) * DIM + sw;

  auto stage = [&](int bf, int k0) {   // 8 global_load_lds per wave
    #pragma unroll
    for (int i = 0; i < 4; ++i) {
      gload16(Abase + (size_t)(i * 8) * DIM + k0, &As[bf][(wid * 32 + i * 8) * 64]);
      gload16(Bbase + (size_t)(i * 8) * DIM + k0, &Bs[bf][(wid * 32 + i * 8) * 64]);
    }
  };

  const int NT = DIM / 64;   // 12
  stage(0, 0);
  stage(1, 64);
  asm volatile("s_waitcnt vmcnt(8)\n\ts_barrier" ::: "memory");  // tile0 ready
  int bf = 0;
  for (int t = 0; t < NT; ++t) {
    #pragma unroll
    for (int kk = 0; kk < 2; ++kk) {
      bf16x8 a[4], bfr[4];
      #pragma unroll
      for (int m = 0; m < 4; ++m)
        a[m] = *(const bf16x8*)&As[bf][(wr * 64 + m * 16 + lo) * 64
                                       + ((kk * 32 + hi * 8) ^ xsw)];
      #pragma unroll
      for (int n = 0; n < 4; ++n)
        bfr[n] = *(const bf16x8*)&Bs[bf][(wc * 64 + n * 16 + lo) * 64
                                         + ((kk * 32 + hi * 8) ^ xsw)];
      #pragma unroll
      for (int m = 0; m < 4; ++m)
        #pragma unroll
        for (int n = 0; n < 4; ++n)
          acc[m][n] = __builtin_amdgcn_mfma_f32_16x16x32_bf16(a[m], bfr[n], acc[m][n], 0, 0, 0);
    }
    if (t < NT - 1) {
      asm volatile("s_barrier" ::: "memory");          // all done reading bf
      if (t + 2 < NT) {
        stage(bf, (t + 2) * 64);                       // into bf; in flight
        asm volatile("s_waitcnt vmcnt(8)\n\ts_barrier" ::: "memory"); // t+1 ready
      } else {
        asm volatile("s_waitcnt vmcnt(0)\n\ts_barrier" ::: "memory"); // last tile
      }
    }
    bf ^= 1;
  }

  // ---- fused epilogue (bitwise-identical LN butterfly) ----
  const int col0 = n0 + wc * 64;           // 64-aligned => one head per wave
  const int hglob = col0 >> 6;             // 0..35
  const int htype = hglob / HEADS;         // 0=q 1=k 2=v
  const int hidx  = hglob - htype * HEADS;
  const float* bp = bias + col0 + lo;

  float gl[4], bl[4];
  if (htype == 0) {
    #pragma unroll
    for (int nt = 0; nt < 4; ++nt) { gl[nt] = gq[nt * 16 + lo]; bl[nt] = bq[nt * 16 + lo]; }
  } else if (htype == 1) {
    #pragma unroll
    for (int nt = 0; nt < 4; ++nt) { gl[nt] = gk[nt * 16 + lo]; bl[nt] = bk[nt * 16 + lo]; }
  }

  #pragma unroll
  for (int m = 0; m < 4; ++m) {
    #pragma unroll
    for (int r = 0; r < 4; ++r) {
      const int grow = m0 + wr * 64 + m * 16 + hi * 4 + r;
      if (grow < MROWS) {          // uniform across each 16-lane lo-group
        const int brow = grow / NSEQ;
        const int n1 = grow - brow * NSEQ;
        const int bh = brow * HEADS + hidx;
        float v[4];
        #pragma unroll
        for (int nt = 0; nt < 4; ++nt) v[nt] = acc[m][nt][r] + bp[nt * 16];
        if (htype == 2) {
          short* dst = vb + ((size_t)bh * NKPAD + n1) * DH + lo;
          #pragma unroll
          for (int nt = 0; nt < 4; ++nt) dst[nt * 16] = (short)f2bf(v[nt]);
        } else {
          // exact butterfly emulation (same operand pairing as ln_qk):
          float s2v[4];
          #pragma unroll
          for (int nt = 0; nt < 4; ++nt) s2v[nt] = v[nt] * v[nt];
          float t[4], t2[4];
          #pragma unroll
          for (int nt = 0; nt < 4; ++nt) {    // off = 32  (d^32 <=> nt^2)
            t[nt]  = v[nt]   + v[nt ^ 2];
            t2[nt] = s2v[nt] + s2v[nt ^ 2];
          }
          float u  = t[0]  + t[1];            // off = 16  (nt^1; all nt equal)
          float u2 = t2[0] + t2[1];
          u  += __shfl_xor(u,  8);  u2 += __shfl_xor(u2, 8);   // off = 8
          u  += __shfl_xor(u,  4);  u2 += __shfl_xor(u2, 4);   // off = 4
          u  += __shfl_xor(u,  2);  u2 += __shfl_xor(u2, 2);   // off = 2
          u  += __shfl_xor(u,  1);  u2 += __shfl_xor(u2, 1);   // off = 1
          const float inv64 = 1.f / 64.f;
          const float mean = u * inv64;
          const float var  = u2 * inv64 - mean * mean;
          const float rr = rsqrtf(var + 1e-5f);
          if (htype == 0) {
            short* dst = qb + ((size_t)bh * QPAD + n1) * DH + lo;
            #pragma unroll
            for (int nt = 0; nt < 4; ++nt)
              dst[nt * 16] = (short)f2bf(((v[nt] - mean) * rr * gl[nt] + bl[nt]) * QSCALE);
          } else {
            short* dst = kb + ((size_t)bh * NKPAD + n1) * DH + lo;
            #pragma unroll
            for (int nt = 0; nt < 4; ++nt)
              dst[nt * 16] = (short)f2bf((v[nt] - mean) * rr * gl[nt] + bl[nt]);
          }
        }
      }
    }
  }
}

// ---------------------------------------------------------------------------
// Generic bf16 MFMA GEMM (proj): C[M,N]f32 = A . Bt^T + bias. 128x128 tile,
// R17-proven counted-vmcnt pipelined staging + swizzled LDS.
// ---------------------------------------------------------------------------
__global__ __launch_bounds__(256) void gemm_bf16_kernel(
    const short* __restrict__ A, const short* __restrict__ Bt,
    const float* __restrict__ bias, float* __restrict__ C,
    int M, int N, int K) {
  __shared__ short As[2][128 * 64];
  __shared__ short Bs[2][128 * 64];
  const int tid = threadIdx.x;
  const int wid = tid >> 6, lane = tid & 63;
  const int lo = lane & 15, hi = lane >> 4;
  const int wr = wid >> 1, wc = wid & 1;
  const int xsw = (lo & 7) << 3;

  const int nwg = gridDim.x * gridDim.y;
  int bid = blockIdx.y * gridDim.x + blockIdx.x;
  {
    const int q = nwg >> 3, rr = nwg & 7;
    const int xcd = bid & 7, idx = bid >> 3;
    bid = (xcd < rr ? xcd * (q + 1) : rr * (q + 1) + (xcd - rr) * q) + idx;
  }
  const int m0 = (bid / gridDim.x) * 128, n0 = (bid % gridDim.x) * 128;

  const int rl = lane >> 3;
  const int sw = ((lane & 7) ^ (lane >> 3)) << 3;

  f32x4 acc[4][4];
  #pragma unroll
  for (int m = 0; m < 4; ++m)
    #pragma unroll
    for (int n = 0; n < 4; ++n)
      acc[m][n][0] = acc[m][n][1] = acc[m][n][2] = acc[m][n][3] = 0.f;

  const short* Abase = A + (size_t)(m0 + wid * 32 + rl) * K + sw;
  const short* Bbase = Bt + (size_t)(n0 + wid * 32 + rl) * K + sw;

  auto stage = [&](int bf, int k0) {   // 8 global_load_lds per wave
    #pragma unroll
    for (int i = 0; i < 4; ++i) {
      gload16(Abase + (size_t)(i * 8) * K + k0, &As[bf][(wid * 32 + i * 8) * 64]);
      gload16(Bbase + (size_t)(i * 8) * K + k0, &Bs[bf][(wid * 32 + i * 8) * 64]);
    }
  };

  const int NT = K / 64;
  stage(0, 0);
  if (NT > 1) stage(1, 64);
  asm volatile("s_waitcnt vmcnt(8)\n\ts_barrier" ::: "memory");
  int bf = 0;
  for (int t = 0; t < NT; ++t) {
    #pragma unroll
    for (int kk = 0; kk < 2; ++kk) {
      bf16x8 a[4], bfr[4];
      #pragma unroll
      for (int m = 0; m < 4; ++m)
        a[m] = *(const bf16x8*)&As[bf][(wr * 64 + m * 16 + lo) * 64
                                       + ((kk * 32 + hi * 8) ^ xsw)];
      #pragma unroll
      for (int n = 0; n < 4; ++n)
        bfr[n] = *(const bf16x8*)&Bs[bf][(wc * 64 + n * 16 + lo) * 64
                                         + ((kk * 32 + hi * 8) ^ xsw)];
      #pragma unroll
      for (int m = 0; m < 4; ++m)
        #pragma unroll
        for (int n = 0; n < 4; ++n)
          acc[m][n] = __builtin_amdgcn_mfma_f32_16x16x32_bf16(a[m], bfr[n], acc[m][n], 0, 0, 0);
    }
    if (t < NT - 1) {
      asm volatile("s_barrier" ::: "memory");
      if (t + 2 < NT) {
        stage(bf, (t + 2) * 64);
        asm volatile("s_waitcnt vmcnt(8)\n\ts_barrier" ::: "memory");
      } else {
        asm volatile("s_waitcnt vmcnt(0)\n\ts_barrier" ::: "memory");
      }
    }
    bf ^= 1;
  }

  #pragma unroll
  for (int m = 0; m < 4; ++m) {
    #pragma unroll
    for (int r = 0; r < 4; ++r) {
      const int grow = m0 + wr * 64 + m * 16 + hi * 4 + r;
      if (grow < M) {
        float* cp = C + (size_t)grow * N + n0 + wc * 64 + lo;
        const float* bp = bias + n0 + wc * 64 + lo;
        #pragma unroll
        for (int n = 0; n < 4; ++n) cp[n * 16] = acc[m][n][r] + bp[n * 16];
      }
    }
  }
}

// ---------------------------------------------------------------------------
// V transpose: vb bf16 [bh][key][64] -> vt bf16 [bh][d][NKPAD] (zero pad).
// Grid: (17, 96), 256 threads.
// ---------------------------------------------------------------------------
__global__ __launch_bounds__(256) void vt_convert_kernel(
    const short* __restrict__ vb, short* __restrict__ vt) {
  const int kt = blockIdx.x;     // key tile 0..16
  const int bh = blockIdx.y;     // 0..95
  const int t = threadIdx.x;
  __shared__ float tile[64][65];
  const int r = t >> 2;          // 0..63
  const int c0 = (t & 3) * 16;   // 0,16,32,48
  const int grow = kt * 64 + r;  // key index 0..1087

  if (grow < NSEQ) {
    const short* src = vb + ((size_t)bh * NKPAD + grow) * DH + c0;
    bf16x8 a = *(const bf16x8*)src;
    bf16x8 b2 = *(const bf16x8*)(src + 8);
    #pragma unroll
    for (int j = 0; j < 8; ++j) {
      tile[r][c0 + j]     = bf2f(a[j]);
      tile[r][c0 + 8 + j] = bf2f(b2[j]);
    }
  } else {
    #pragma unroll
    for (int j = 0; j < 16; ++j) tile[r][c0 + j] = 0.f;
  }
  __syncthreads();
  bf16x8 w0, w1;
  #pragma unroll
  for (int j = 0; j < 8; ++j) {
    w0[j] = (short)f2bf(tile[c0 + j][r]);
    w1[j] = (short)f2bf(tile[c0 + 8 + j][r]);
  }
  short* dst = vt + ((size_t)bh * DH + r) * NKPAD + kt * 64 + c0;
  *(bf16x8*)dst = w0;
  *(bf16x8*)(dst + 8) = w1;
}

// ---------------------------------------------------------------------------
// MFMA bf16 flash attention v7 (R20): split-stage single-buffered K/V +
// ones-MFMA denominator. Grid: (96, QPAD/128 = 9) -- XCD-local.
// ---------------------------------------------------------------------------
__global__ __launch_bounds__(256) void attn_mfma_kernel(
    const short* __restrict__ qb, const short* __restrict__ kb,
    const short* __restrict__ vt, short* __restrict__ ab) {
  const int bh = blockIdx.x;
  const int b = bh / HEADS, h = bh - (bh / HEADS) * HEADS;
  const int wid = threadIdx.x >> 6;
  const int lane = threadIdx.x & 63;
  const int lo = lane & 15, hi = lane >> 4;
  const int q0 = blockIdx.y * 128;
  const int xsw = (lo & 7) << 3;          // read-side XOR swizzle (shorts)

  __shared__ short Ks[64 * 64];           // swizzled K tile  [key][d]
  __shared__ short Vs[64 * 64];           // swizzled V^T tile [d][key]
  __shared__ short Pb[4][32][72];         // per-wave P buffer

  const short* kg = kb + (size_t)bh * NKPAD * DH;
  const short* vg = vt + (size_t)bh * DH * NKPAD;

  const int sr = wid * 16 + (lane >> 3);               // staging row 0..63
  const int sw = ((lane & 7) ^ (lane >> 3)) << 3;      // pre-swizzled col
  auto stageK = [&](int kt) {
    #pragma unroll
    for (int i = 0; i < 2; ++i)
      gload16(kg + (size_t)(kt * 64 + sr + i * 8) * DH + sw,
              &Ks[wid * 1024 + i * 512]);
  };
  auto stageV = [&](int kt) {
    #pragma unroll
    for (int i = 0; i < 2; ++i)
      gload16(vg + (size_t)(sr + i * 8) * NKPAD + kt * 64 + sw,
              &Vs[wid * 1024 + i * 512]);
  };

  bf16x8 aq[2][2];
  #pragma unroll
  for (int m = 0; m < 2; ++m) {
    const short* qp = qb + (size_t)bh * QPAD * DH
                    + (size_t)(q0 + wid * 32 + m * 16 + lo) * DH + hi * 8;
    aq[m][0] = *(const bf16x8*)qp;
    aq[m][1] = *(const bf16x8*)(qp + 32);
  }

  // ones B-fragment for the denominator MFMA (bf16 1.0 = 0x3F80)
  bf16x8 ones;
  #pragma unroll
  for (int j = 0; j < 8; ++j) ones[j] = (short)0x3F80;

  f32x4 o[2][4];
  f32x4 ol[2];                            // row-sum accumulator (denominator)
  #pragma unroll
  for (int m = 0; m < 2; ++m) {
    #pragma unroll
    for (int nt = 0; nt < 4; ++nt)
      o[m][nt][0] = o[m][nt][1] = o[m][nt][2] = o[m][nt][3] = 0.f;
    ol[m][0] = ol[m][1] = ol[m][2] = ol[m][3] = 0.f;
  }

  stageK(0);
  stageV(0);
  __syncthreads();   // drains vmcnt(0): tile 0 staged & visible

  for (int kt = 0; kt < 17; ++kt) {
    // ---- QK^T (reads Ks) ----
    f32x4 s[2][4];
    #pragma unroll
    for (int m = 0; m < 2; ++m)
      #pragma unroll
      for (int nt = 0; nt < 4; ++nt)
        s[m][nt][0] = s[m][nt][1] = s[m][nt][2] = s[m][nt][3] = 0.f;
    __builtin_amdgcn_s_setprio(1);
    #pragma unroll
    for (int kk = 0; kk < 2; ++kk) {
      bf16x8 kf[4];
      #pragma unroll
      for (int nt = 0; nt < 4; ++nt)
        kf[nt] = *(const bf16x8*)&Ks[(nt * 16 + lo) * 64
                                     + ((kk * 32 + hi * 8) ^ xsw)];
      #pragma unroll
      for (int m = 0; m < 2; ++m)
        #pragma unroll
        for (int nt = 0; nt < 4; ++nt)
          s[m][nt] = __builtin_amdgcn_mfma_f32_16x16x32_bf16(
              aq[m][kk], kf[nt], s[m][nt], 0, 0, 0);
    }
    __builtin_amdgcn_s_setprio(0);

    __syncthreads();                  // all waves done reading Ks
    if (kt < 16) stageK(kt + 1);      // overlaps softmax + PV below

    if (kt == 16) {
      #pragma unroll
      for (int m = 0; m < 2; ++m)
        #pragma unroll
        for (int nt = 0; nt < 4; ++nt)
          if (nt * 16 + lo >= 1)
            s[m][nt][0] = s[m][nt][1] = s[m][nt][2] = s[m][nt][3] = -1e30f;
    }
    // ---- softmax (fixed offset) + P staging (packed bf16 convert) ----
    #pragma unroll
    for (int m = 0; m < 2; ++m)
      #pragma unroll
      for (int nt = 0; nt < 4; ++nt) {
        float p0 = exp2f(s[m][nt][0] - SBOUND);
        float p1 = exp2f(s[m][nt][1] - SBOUND);
        float p2 = exp2f(s[m][nt][2] - SBOUND);
        float p3 = exp2f(s[m][nt][3] - SBOUND);
        unsigned int c01 = cvtpk_bf16(p0, p1);
        unsigned int c23 = cvtpk_bf16(p2, p3);
        unsigned short* pb = (unsigned short*)&Pb[wid][m * 16 + 4 * hi][nt * 16 + lo];
        pb[0]       = (unsigned short)c01;
        pb[72]      = (unsigned short)(c01 >> 16);
        pb[144]     = (unsigned short)c23;
        pb[216]     = (unsigned short)(c23 >> 16);
      }
    // ---- PV (reads Vs) + denominator via ones-MFMA ----
    __builtin_amdgcn_s_setprio(1);
    #pragma unroll
    for (int ks = 0; ks < 2; ++ks) {
      bf16x8 pa0 = *(const bf16x8*)&Pb[wid][lo][ks * 32 + hi * 8];
      bf16x8 pa1 = *(const bf16x8*)&Pb[wid][16 + lo][ks * 32 + hi * 8];
      #pragma unroll
      for (int nt = 0; nt < 4; ++nt) {
        bf16x8 vf = *(const bf16x8*)&Vs[(nt * 16 + lo) * 64
                                        + ((ks * 32 + hi * 8) ^ xsw)];
        o[0][nt] = __builtin_amdgcn_mfma_f32_16x16x32_bf16(pa0, vf, o[0][nt], 0, 0, 0);
        o[1][nt] = __builtin_amdgcn_mfma_f32_16x16x32_bf16(pa1, vf, o[1][nt], 0, 0, 0);
      }
      ol[0] = __builtin_amdgcn_mfma_f32_16x16x32_bf16(pa0, ones, ol[0], 0, 0, 0);
      ol[1] = __builtin_amdgcn_mfma_f32_16x16x32_bf16(pa1, ones, ol[1], 0, 0, 0);
    }
    __builtin_amdgcn_s_setprio(0);

    __syncthreads();                  // all waves done reading Vs; drains
    if (kt < 16) stageV(kt + 1);      //   stageK's vmcnt. V overlaps next QK^T
  }

  // ol[m][r] = row sum (denominator) for row m*16 + 4*hi + r -- no reduce.
  #pragma unroll
  for (int m = 0; m < 2; ++m)
    #pragma unroll
    for (int r = 0; r < 4; ++r) {
      const int qrow = q0 + wid * 32 + m * 16 + 4 * hi + r;
      if (qrow < NSEQ) {
        const float inv = 1.f / ol[m][r];
        short* op = ab + (size_t)(b * NSEQ + qrow) * DIM + h * DH + lo;
        #pragma unroll
        for (int nt = 0; nt < 4; ++nt)
          op[nt * 16] = (short)f2bf(o[m][nt][r] * inv);
      }
    }
}

// ---------------------------------------------------------------------------
// attn_map pass A: per-(b,h) row-0 softmax max & inv-denominator (bf16 in).
// Grid 96, 256 threads. ms[bh] = {max, 1/(sum*HEADS)}.
// ---------------------------------------------------------------------------
__global__ __launch_bounds__(256) void map_ms_kernel(
    const short* __restrict__ qb, const short* __restrict__ kb,
    float* __restrict__ ms) {
  const int bh = blockIdx.x;
  const int tid = threadIdx.x;
  __shared__ float q0s[64];
  __shared__ float red[256];
  if (tid < 64) q0s[tid] = bf2f(qb[(size_t)bh * QPAD * DH + tid]);
  __syncthreads();
  float s[5];
  float lm = -INFINITY;
  #pragma unroll
  for (int sl = 0; sl < 5; ++sl) {
    int j = tid + sl * 256;
    s[sl] = -INFINITY;
    if (j < NSEQ) {
      const short* kp = kb + ((size_t)bh * NKPAD + j) * DH;
      float d0 = 0.f;
      #pragma unroll
      for (int c = 0; c < 8; ++c) {
        bf16x8 kv = *(const bf16x8*)(kp + c * 8);
        #pragma unroll
        for (int e = 0; e < 8; ++e) d0 += q0s[c * 8 + e] * bf2f(kv[e]);
      }
      s[sl] = d0;
      lm = fmaxf(lm, d0);
    }
  }
  red[tid] = lm; __syncthreads();
  for (int off = 128; off > 0; off >>= 1) {
    if (tid < off) red[tid] = fmaxf(red[tid], red[tid + off]);
    __syncthreads();
  }
  const float Mx = red[0]; __syncthreads();
  float ls = 0.f;
  #pragma unroll
  for (int sl = 0; sl < 5; ++sl) {
    int j = tid + sl * 256;
    if (j < NSEQ) ls += exp2f(s[sl] - Mx);
  }
  red[tid] = ls; __syncthreads();
  for (int off = 128; off > 0; off >>= 1) {
    if (tid < off) red[tid] += red[tid + off];
    __syncthreads();
  }
  if (tid == 0) {
    ms[bh * 2]     = Mx;
    ms[bh * 2 + 1] = 1.f / (red[0] * (float)HEADS);
  }
}

// ---------------------------------------------------------------------------
// attn_map pass B: map[b][j-1] = sum_h exp2(q0_h . k_jh - M_h) * inv_h.
// Grid (4, 8), 256 threads; thread handles one (b, j). bf16 inputs.
// ---------------------------------------------------------------------------
__global__ __launch_bounds__(256) void map_p_kernel(
    const short* __restrict__ qb, const short* __restrict__ kb,
    const float* __restrict__ ms, float* __restrict__ map) {
  const int b = blockIdx.y;
  const int j = blockIdx.x * 256 + threadIdx.x + 1;   // 1..1024
  const int tid = threadIdx.x;
  __shared__ float q0s[768];
  __shared__ float msb[24];
  for (int idx = tid; idx < 768; idx += 256) {
    const int h = idx >> 6, d = idx & 63;
    q0s[idx] = bf2f(qb[(size_t)(b * HEADS + h) * QPAD * DH + d]);
  }
  if (tid < 24) msb[tid] = ms[b * HEADS * 2 + tid];
  __syncthreads();
  float acc = 0.f;
  #pragma unroll
  for (int h = 0; h < HEADS; ++h) {
    const short* kp = kb + ((size_t)(b * HEADS + h) * NKPAD + j) * DH;
    float d0 = 0.f;
    #pragma unroll
    for (int c = 0; c < 8; ++c) {
      bf16x8 kv = *(const bf16x8*)(kp + c * 8);
      const float* qp = &q0s[h * DH + c * 8];
      #pragma unroll
      for (int e = 0; e < 8; ++e) d0 += qp[e] * bf2f(kv[e]);
    }
    acc += exp2f(d0 - msb[h * 2]) * msb[h * 2 + 1];
  }
  map[(size_t)b * (NSEQ - 1) + j - 1] = acc;
}

// ---------------------------------------------------------------------------
extern "C" void kernel_launch(void* const* d_in, const int* in_sizes, int n_in,
                              void* d_out, int out_size, void* d_ws, size_t ws_size,
                              hipStream_t stream) {
  const float* x     = (const float*)d_in[0];
  const float* Wqkv  = (const float*)d_in[1];
  const float* bqkv  = (const float*)d_in[2];
  const float* Wproj = (const float*)d_in[3];
  const float* bproj = (const float*)d_in[4];
  const float* gq    = (const float*)d_in[5];
  const float* betaq = (const float*)d_in[6];
  const float* gk    = (const float*)d_in[7];
  const float* betak = (const float*)d_in[8];

  short* xb  = (short*)d_ws;                              // [8448,768] bf16 (also attn out)
  short* qb  = xb + (size_t)MPAD * DIM;                   // [96,1152,64] bf16
  short* kb  = qb + (size_t)NBH * QPAD * DH;              // [96,1088,64] bf16
  short* vb  = kb + (size_t)NBH * NKPAD * DH;             // [96,1088,64] bf16
  short* vt  = vb + (size_t)NBH * NKPAD * DH;             // [96,64,1088] bf16
  short* wqt = vt + (size_t)NBH * DH * NKPAD;             // [2304,768] bf16
  short* wpt = wqt + (size_t)C3 * DIM;                    // [768,768] bf16
  float* ms  = (float*)(wpt + (size_t)DIM * DIM);         // [96,2] f32
  float* out = (float*)d_out;                             // [8200,768]
  float* map = out + (size_t)MROWS * DIM;                 // [8,1024]

  // 0) conversions
  convert_x_kernel<<<MPAD * DIM / 2048, 256, 0, stream>>>(x, xb);
  {
    dim3 grid(C3 / 64, DIM / 64);
    wtrans_kernel<<<grid, 256, 0, stream>>>(Wqkv, wqt, DIM, C3);
  }
  {
    dim3 grid(DIM / 64, DIM / 64);
    wtrans_kernel<<<grid, 256, 0, stream>>>(Wproj, wpt, DIM, DIM);
  }
  // 1) Fused QKV GEMM + LN (pipelined vmcnt staging) -> qb/kb/vb bf16
  {
    dim3 grid(C3 / 128, MPAD / 128);
    gemm_qkv_kernel<<<grid, 256, 0, stream>>>(xb, wqt, bqkv,
                                              gq, betaq, gk, betak, qb, kb, vb);
  }
  // 2) V transpose (bf16 in, bf16 out)
  {
    dim3 grid(17, NBH);
    vt_convert_kernel<<<grid, 256, 0, stream>>>(vb, vt);
  }
  // 3) MFMA attention v7 (split-stage, ones-MFMA denominator) -> bf16 into xb
  {
    dim3 grid(NBH, QPAD / 128);
    attn_mfma_kernel<<<grid, 256, 0, stream>>>(qb, kb, vt, xb);
  }
  // 4) attn_map (bf16 path, two passes)
  map_ms_kernel<<<NBH, 256, 0, stream>>>(qb, kb, ms);
  {
    dim3 grid(4, BS);
    map_p_kernel<<<grid, 256, 0, stream>>>(qb, kb, ms, map);
  }
  // 5) out = attn_out @ Wproj + bproj (pipelined vmcnt staging)
  {
    dim3 grid(DIM / 128, MPAD / 128);
    gemm_bf16_kernel<<<grid, 256, 0, stream>>>(xb, wpt, bproj, out, MROWS, DIM, DIM);
  }
}